// Round 4
// baseline (274.528 us; speedup 1.0000x reference)
//
#include <hip/hip_runtime.h>
#include <hip/hip_bf16.h>

#define N 8192
#define FIN 512
#define FOUT 256

typedef __attribute__((ext_vector_type(8))) short bf16x8;
typedef __attribute__((ext_vector_type(4))) float f32x4;

__device__ __forceinline__ unsigned short f2bf(float x) {
  unsigned int u = __float_as_uint(x);
  return (unsigned short)((u + 0x7FFFu + ((u >> 16) & 1u)) >> 16);
}

__device__ __forceinline__ void load_lds16(const void* g, void* l) {
  __builtin_amdgcn_global_load_lds(
      (const __attribute__((address_space(1))) void*)g,
      (__attribute__((address_space(3))) void*)l, 16, 0, 0);
}

// ---------------------------------------------------------------------------
// K1: h = features(8192x512) @ W(512x256), fp32 vector GEMM, 64x64 tile.
// Epilogue also writes hT (bf16, [FOUT][N]) for the fused kernel's B staging.
// ---------------------------------------------------------------------------
__global__ __launch_bounds__(256) void gat_k1_gemm_h(
    const float* __restrict__ A, const float* __restrict__ W,
    float* __restrict__ h, unsigned short* __restrict__ hT) {
  __shared__ __align__(16) float As[16][68];
  __shared__ __align__(16) float Bs[16][64];
  const int tid = threadIdx.x;
  const int tx = tid & 15, ty = tid >> 4;
  const int nb = blockIdx.x * 64, mb = blockIdx.y * 64;
  float acc[4][4] = {};
  for (int k0 = 0; k0 < FIN; k0 += 16) {
#pragma unroll
    for (int i = 0; i < 4; ++i) {
      int e = tid + 256 * i;
      int m = e >> 4, k = e & 15;
      As[k][m] = A[(size_t)(mb + m) * FIN + k0 + k];
      int n2 = e & 63, k2 = e >> 6;
      Bs[k2][n2] = W[(size_t)(k0 + k2) * FOUT + nb + n2];
    }
    __syncthreads();
#pragma unroll
    for (int k = 0; k < 16; ++k) {
      float4 av = *reinterpret_cast<const float4*>(&As[k][ty * 4]);
      float4 bv = *reinterpret_cast<const float4*>(&Bs[k][tx * 4]);
      float aa[4] = {av.x, av.y, av.z, av.w};
      float bb[4] = {bv.x, bv.y, bv.z, bv.w};
#pragma unroll
      for (int i = 0; i < 4; ++i)
#pragma unroll
        for (int j = 0; j < 4; ++j) acc[i][j] = fmaf(aa[i], bb[j], acc[i][j]);
    }
    __syncthreads();
  }
#pragma unroll
  for (int i = 0; i < 4; ++i) {
    int m = mb + ty * 4 + i;
#pragma unroll
    for (int j = 0; j < 4; ++j) {
      int n = nb + tx * 4 + j;
      h[(size_t)m * FOUT + n] = acc[i][j];
      hT[(size_t)n * N + m] = f2bf(acc[i][j]);
    }
  }
}

// ---------------------------------------------------------------------------
// K2: hs[i] = h[i,:]@a[:256], hd[i] = h[i,:]@a[256:]. One wave per row.
// ---------------------------------------------------------------------------
__global__ __launch_bounds__(256) void gat_k2_hshd(
    const float* __restrict__ h, const float* __restrict__ a,
    float* __restrict__ hs, float* __restrict__ hd) {
  const int wid = threadIdx.x >> 6;
  const int lane = threadIdx.x & 63;
  const int row = blockIdx.x * 4 + wid;
  float ps = 0.f, pd = 0.f;
#pragma unroll
  for (int i = 0; i < 4; ++i) {
    int c = lane + 64 * i;
    float v = h[(size_t)row * FOUT + c];
    ps += v * a[c];
    pd += v * a[FOUT + c];
  }
#pragma unroll
  for (int off = 32; off >= 1; off >>= 1) {
    ps += __shfl_down(ps, off);
    pd += __shfl_down(pd, off);
  }
  if (lane == 0) {
    hs[row] = ps;
    hd[row] = pd;
  }
}

// ---------------------------------------------------------------------------
// FK: fused masked-softmax + (attention @ h).
// 256 blocks x 1024 threads (1 block/CU, 16 waves). BM=32 rows/block.
// Phase 1: one streaming pass of this block's adj rows (8B/lane float2,
//   thread t owns row r=t>>5 cols {c*2, c*2+1} of every 64-wide K-tile);
//   accumulates softmax denominator s_r (no max subtraction: logits are
//   O(10), exp is f32-safe; masked terms exactly 0 like ref's exp(-1e9))
//   and packs the adjacency bits into 8 VGPRs (2 bits x 128 tiles).
//   s reduced across the 32 lanes owning the row -> inv kept in-register.
// Phase 2: 128 K-tiles. Per tile t: stage hT tile -> Bs[t&1] via
//   global_load_lds (pre-swizzled source, linear LDS); recompute
//   p = e*inv from bits+hd_s, store att f32 (output, written once) and
//   bf16 -> As[t&1] (XOR-swizzled); MFMA(t-1) from buf[(t&1)^1];
//   one barrier/iter (drain doubles as the staging completion wait).
//   Waves: wm=w>>3 row-half (16 rows), wn=w&7 col-tile (32 cols), acc 1x2.
// ---------------------------------------------------------------------------
__global__ __launch_bounds__(1024, 4) void gat_fused(
    const float* __restrict__ adj, const float* __restrict__ hs,
    const float* __restrict__ hd, const unsigned short* __restrict__ hT,
    float* __restrict__ att, float* __restrict__ C) {
  __shared__ __align__(16) float hd_s[N];                // 32 KB
  __shared__ __align__(16) unsigned short As[2][32 * 64];   // 8 KB
  __shared__ __align__(16) unsigned short Bs[2][256 * 64];  // 64 KB

  const int tid = threadIdx.x;
  const int lane = tid & 63;
  const int w = tid >> 6;            // 0..15
  const int wm = w >> 3, wn = w & 7;
  const int g = lane >> 4, rsel = lane & 15;
  const int row0 = blockIdx.x * 32;
  const int r = tid >> 5;            // owned row 0..31
  const int c = tid & 31;            // owned col-pair 0..31

  // stage hd (8 floats/thread)
#pragma unroll
  for (int i = 0; i < 2; ++i) {
    int j = tid * 8 + i * 4;
    *reinterpret_cast<float4*>(&hd_s[j]) =
        *reinterpret_cast<const float4*>(&hd[j]);
  }
  const float hsv = hs[row0 + r];
  __syncthreads();

  // ---- phase 1: denominator + adjacency bits ----
  unsigned int bits[8];
  float s = 0.f;
  const float* arow = adj + (size_t)(row0 + r) * N + c * 2;
#pragma unroll
  for (int to = 0; to < 8; ++to) {
    unsigned int wb = 0;
#pragma unroll 4
    for (int qi = 0; qi < 16; ++qi) {
      int q = to * 16 + qi;
      float2 a2 = *reinterpret_cast<const float2*>(arow + q * 64);
      float2 h2 = *reinterpret_cast<const float2*>(&hd_s[q * 64 + c * 2]);
      float x0 = hsv + h2.x, x1 = hsv + h2.y;
      float l0 = fmaxf(x0, 0.01f * x0);
      float l1 = fmaxf(x1, 0.01f * x1);
      unsigned int b0 = (a2.x != 0.f) ? 1u : 0u;
      unsigned int b1 = (a2.y != 0.f) ? 1u : 0u;
      s += (b0 ? __expf(l0) : 0.f) + (b1 ? __expf(l1) : 0.f);
      wb |= (b0 | (b1 << 1)) << (qi * 2);
    }
    bits[to] = wb;
  }
#pragma unroll
  for (int off = 16; off >= 1; off >>= 1) s += __shfl_xor(s, off);
  const float inv = 1.f / s;

  // ---- phase 2: att write + GEMM ----
  // B staging: 2048 16B-slots; slot s2 -> n=s2>>3, k-group kg=s2&7,
  // source pre-swizzled kg^(n&7) so linear LDS == swizzled layout.
  const unsigned short* bsrc0;
  const unsigned short* bsrc1;
  int bofs0, bofs1;
  {
    int s0 = tid, n0 = s0 >> 3, k0 = s0 & 7;
    bsrc0 = hT + (size_t)n0 * N + (k0 ^ (n0 & 7)) * 8;
    bofs0 = s0 * 16;
    int s1 = tid + 1024, n1 = s1 >> 3, k1 = s1 & 7;
    bsrc1 = hT + (size_t)n1 * N + (k1 ^ (n1 & 7)) * 8;
    bofs1 = s1 * 16;
  }
  float* aout = att + (size_t)(row0 + r) * N + c * 2;
  const int awbyte = r * 128 + ((c * 4) ^ ((r & 7) << 4));
  const int fr = wm * 16 + rsel;
  const int abase = fr * 128;
  const int asw = (fr & 7) << 4;

  f32x4 acc[2] = {};

#pragma unroll
  for (int to = 0; to < 8; ++to) {
    unsigned int wb = bits[to];
    for (int ti = 0; ti < 16; ++ti) {
      const int t = to * 16 + ti;
      const int kb = t * 64;
      char* Bw = reinterpret_cast<char*>(Bs[t & 1]);
      // (1) stage hT tile t directly to LDS (in flight until the barrier)
      load_lds16(bsrc0 + kb, Bw + bofs0);
      load_lds16(bsrc1 + kb, Bw + bofs1);
      // (2) e-tile t: att store + bf16 -> As[t&1]
      {
        float2 h2 = *reinterpret_cast<const float2*>(&hd_s[kb + c * 2]);
        unsigned int duo = wb >> (ti * 2);
        float x0 = hsv + h2.x, x1 = hsv + h2.y;
        float l0 = fmaxf(x0, 0.01f * x0);
        float l1 = fmaxf(x1, 0.01f * x1);
        float p0 = (duo & 1) ? __expf(l0) * inv : 0.f;
        float p1 = (duo & 2) ? __expf(l1) * inv : 0.f;
        *reinterpret_cast<float2*>(aout + kb) = make_float2(p0, p1);
        unsigned int pk = (unsigned)f2bf(p0) | ((unsigned)f2bf(p1) << 16);
        *reinterpret_cast<unsigned int*>(
            reinterpret_cast<char*>(As[t & 1]) + awbyte) = pk;
      }
      // (3) MFMA tile t-1 from the other buffer
      if (t > 0) {
        const char* Ar = reinterpret_cast<const char*>(As[(t & 1) ^ 1]);
        const char* Br = reinterpret_cast<const char*>(Bs[(t & 1) ^ 1]);
#pragma unroll
        for (int ks = 0; ks < 2; ++ks) {
          bf16x8 af = *reinterpret_cast<const bf16x8*>(
              Ar + abase + ((ks * 64 + g * 16) ^ asw));
#pragma unroll
          for (int f = 0; f < 2; ++f) {
            int n = wn * 32 + f * 16 + rsel;
            bf16x8 bg = *reinterpret_cast<const bf16x8*>(
                Br + n * 128 + ((ks * 64 + g * 16) ^ ((n & 7) << 4)));
            acc[f] = __builtin_amdgcn_mfma_f32_16x16x32_bf16(af, bg, acc[f],
                                                             0, 0, 0);
          }
        }
      }
      // (4) barrier: orders buf writes/reads, drains staging loads
      __syncthreads();
    }
  }
  // epilogue: MFMA tile 127 (buf 1)
  {
    const char* Ar = reinterpret_cast<const char*>(As[1]);
    const char* Br = reinterpret_cast<const char*>(Bs[1]);
#pragma unroll
    for (int ks = 0; ks < 2; ++ks) {
      bf16x8 af = *reinterpret_cast<const bf16x8*>(
          Ar + abase + ((ks * 64 + g * 16) ^ asw));
#pragma unroll
      for (int f = 0; f < 2; ++f) {
        int n = wn * 32 + f * 16 + rsel;
        bf16x8 bg = *reinterpret_cast<const bf16x8*>(
            Br + n * 128 + ((ks * 64 + g * 16) ^ ((n & 7) << 4)));
        acc[f] = __builtin_amdgcn_mfma_f32_16x16x32_bf16(af, bg, acc[f],
                                                         0, 0, 0);
      }
    }
  }
  // C write: C/D layout col=lane&15, row=(lane>>4)*4+reg
#pragma unroll
  for (int f = 0; f < 2; ++f)
#pragma unroll
    for (int rr = 0; rr < 4; ++rr) {
      int row = row0 + wm * 16 + g * 4 + rr;
      int col = wn * 32 + f * 16 + rsel;
      C[(size_t)row * FOUT + col] = acc[f][rr];
    }
}

extern "C" void kernel_launch(void* const* d_in, const int* in_sizes, int n_in,
                              void* d_out, int out_size, void* d_ws, size_t ws_size,
                              hipStream_t stream) {
  const float* features = (const float*)d_in[0];
  const float* adj = (const float*)d_in[1];
  const float* W = (const float*)d_in[2];
  const float* a = (const float*)d_in[3];

  float* out = (float*)d_out;           // [N][FOUT]
  float* att = out + (size_t)N * FOUT;  // [N][N]

  char* ws = (char*)d_ws;
  float* h = (float*)ws;                                              // 8 MB
  unsigned short* hT = (unsigned short*)(ws + (size_t)N * FOUT * 4);  // 4 MB
  float* hs = (float*)(ws + (size_t)N * FOUT * 4 + (size_t)N * FOUT * 2);
  float* hd = hs + N;

  hipLaunchKernelGGL(gat_k1_gemm_h, dim3(FOUT / 64, N / 64), dim3(256), 0,
                     stream, features, W, h, hT);
  hipLaunchKernelGGL(gat_k2_hshd, dim3(N / 4), dim3(256), 0, stream, h, a, hs,
                     hd);
  hipLaunchKernelGGL(gat_fused, dim3(N / 32), dim3(1024), 0, stream, adj, hs,
                     hd, hT, att, out);
}